// Round 5
// baseline (294.604 us; speedup 1.0000x reference)
//
#include <hip/hip_runtime.h>
#include <cstddef>
#include <cmath>

#define FFT_N    512
#define IMG_PIX  (FFT_N * FFT_N)
#define NIMG     48          // B*C
#define NPAIR    24
#define KSZ      15
#define KK       (KSZ * KSZ)
#define BAL      0.1f
#define TWO_PI   6.283185307179586f
#define NV       257                         // rfft half-width (v = 0..256)
#define PLANE    ((size_t)FFT_N * NV)        // elems per image half-spectrum plane
#define EXSZ     576                         // per-wave exchange buffer (floats)

__device__ __forceinline__ float2 cadd(float2 a, float2 b) { return make_float2(a.x + b.x, a.y + b.y); }
__device__ __forceinline__ float2 csub(float2 a, float2 b) { return make_float2(a.x - b.x, a.y - b.y); }
__device__ __forceinline__ float2 cmul(float2 a, float2 b) {
  return make_float2(a.x * b.x - a.y * b.y, a.x * b.y + a.y * b.x);
}
__device__ __forceinline__ int ex1(int c, int b, int g) { return 72 * c + 8 * b + g; }
__device__ __forceinline__ int ex2(int c, int e, int g) { return 72 * c + 9 * e + g; }

// Wave-local ordering fence: exchange buffers are wave-private and DS ops from
// one wave complete in order, so no block barrier is needed — only a compiler
// fence so LDS reads/writes are not reordered across the exchange phases.
__device__ __forceinline__ void wsync() {
  asm volatile("" ::: "memory");
  __builtin_amdgcn_wave_barrier();
  asm volatile("" ::: "memory");
}

// DFT8 over the 8 registers: out[k] = sum_a in[a] e^{-+2pi i a k/8} (INV => +).
template <bool INV>
__device__ __forceinline__ void dft8(float2 r[8]) {
  const float RH = 0.70710678118654752440f;
  float2 s0 = cadd(r[0], r[4]), s1 = cadd(r[1], r[5]), s2 = cadd(r[2], r[6]), s3 = cadd(r[3], r[7]);
  float2 d0 = csub(r[0], r[4]), d1 = csub(r[1], r[5]), d2 = csub(r[2], r[6]), d3 = csub(r[3], r[7]);
  if (!INV) {
    d1 = make_float2(RH * (d1.x + d1.y), RH * (d1.y - d1.x));   // *W8^1
    d2 = make_float2(d2.y, -d2.x);                              // *-i
    d3 = make_float2(RH * (d3.y - d3.x), RH * (-d3.x - d3.y));  // *W8^3
  } else {
    d1 = make_float2(RH * (d1.x - d1.y), RH * (d1.x + d1.y));   // *W8^-1
    d2 = make_float2(-d2.y, d2.x);                              // *+i
    d3 = make_float2(RH * (-d3.x - d3.y), RH * (d3.x - d3.y));  // *W8^-3
  }
  float2 t0 = cadd(s0, s2), t1 = csub(s0, s2), t2 = cadd(s1, s3), t3 = csub(s1, s3);
  t3 = INV ? make_float2(-t3.y, t3.x) : make_float2(t3.y, -t3.x);
  float2 E0 = cadd(t0, t2), E1 = cadd(t1, t3), E2 = csub(t0, t2), E3 = csub(t1, t3);
  t0 = cadd(d0, d2); t1 = csub(d0, d2); t2 = cadd(d1, d3); t3 = csub(d1, d3);
  t3 = INV ? make_float2(-t3.y, t3.x) : make_float2(t3.y, -t3.x);
  r[0] = E0; r[2] = E1; r[4] = E2; r[6] = E3;
  r[1] = cadd(t0, t2); r[3] = cadd(t1, t3); r[5] = csub(t0, t2); r[7] = csub(t1, t3);
}

// 512-pt FFT, one wave per line, data in 8 regs. tw[k] = e^{-2pi i k/512}.
// Forward: input r[a] = x[64a + j] -> lane 8c+e, reg f holds X[c + 8e + 64f]
// (bitswap-lanes => lane-linear). Inverse: conjugate graph, same geometry.
template <bool INV>
__device__ void fft512_reg(float2 r[8], float* ere, float* eim, const float2* tw, int j) {
  const int hi = j >> 3, lo = j & 7;
  dft8<INV>(r);                         // over a -> regs c
  #pragma unroll
  for (int c = 1; c < 8; ++c) {         // twiddle W64^{b c}
    float2 w = tw[(8 * hi * c) & 511];
    if (INV) w.y = -w.y;
    r[c] = cmul(r[c], w);
  }
  #pragma unroll
  for (int c = 0; c < 8; ++c) { int a = ex1(c, hi, lo); ere[a] = r[c].x; eim[a] = r[c].y; }
  wsync();
  #pragma unroll
  for (int b = 0; b < 8; ++b) { int a = ex1(hi, b, lo); r[b] = make_float2(ere[a], eim[a]); }
  dft8<INV>(r);                         // over b -> regs e
  {                                     // twiddle W512^{g(c+8e)} via recurrence
    float2 base = tw[(lo * hi) & 511];
    float2 step = tw[(8 * lo) & 511];
    if (INV) { base.y = -base.y; step.y = -step.y; }
    #pragma unroll
    for (int e = 0; e < 8; ++e) { r[e] = cmul(r[e], base); base = cmul(base, step); }
  }
  wsync();                              // ex1 reads must precede ex2 writes
  #pragma unroll
  for (int e = 0; e < 8; ++e) { int a = ex2(hi, e, lo); ere[a] = r[e].x; eim[a] = r[e].y; }
  wsync();
  #pragma unroll
  for (int g = 0; g < 8; ++g) { int a = ex2(hi, lo, g); r[g] = make_float2(ere[a], eim[a]); }
  dft8<INV>(r);                         // over g -> regs f
}

// lane bit-swap (hi3<->lo3): converts (c,e)-lane layout <-> lane-linear layout.
__device__ __forceinline__ void bitswap_lanes(float2 r[8], int j) {
  int src = ((j & 7) << 3) | (j >> 3);
  #pragma unroll
  for (int f = 0; f < 8; ++f) {
    r[f].x = __shfl(r[f].x, src);
    r[f].y = __shfl(r[f].y, src);
  }
}

__device__ __forceinline__ void fill_tw(float2* tw, int t) {
  float s, c;
  float ang = -TWO_PI * (float)t / (float)FFT_N;
  sincosf(ang, &s, &c); tw[t] = make_float2(c, s);
  ang = -TWO_PI * (float)(t + 256) / (float)FFT_N;
  sincosf(ang, &s, &c); tw[t + 256] = make_float2(c, s);
}

// PSF row-DFT, transposed: St[img][v][i] = sum_j f[i][j] e^{-2pi i v(j-7)/512},
// v in [0,256]. Contiguous 15-float2 run per (img,v) for scalar loads later.
__global__ __launch_bounds__(256) void k_psf(
    const float* __restrict__ filters, float2* __restrict__ St) {
  __shared__ float fs[KK];
  int img = blockIdx.x;
  int t = threadIdx.x;
  if (t < KK) fs[t] = filters[(size_t)img * KK + t];
  __syncthreads();
  for (int v = t; v < NV; v += 256) {
    float cs[KSZ], sn[KSZ];
    #pragma unroll
    for (int jj = 0; jj < KSZ; ++jj) {
      float ang = -TWO_PI * (float)(v * (jj - 7)) / (float)FFT_N;
      sincosf(ang, &sn[jj], &cs[jj]);
    }
    float2* dst = St + ((size_t)img * NV + v) * KSZ;
    #pragma unroll
    for (int i = 0; i < KSZ; ++i) {
      float2 s = make_float2(0.f, 0.f);
      #pragma unroll
      for (int jj = 0; jj < KSZ; ++jj) {
        float fv = fs[i * KSZ + jj];
        s.x += fv * cs[jj];
        s.y += fv * sn[jj];
      }
      dst[i] = s;
    }
  }
}

// Row FFT of packed pair (z = yA + i yB) + Hermitian unpack; writes per-image
// half-spectrum planes zh1[img][row][v], v in [0,256]. One wave per row.
__global__ __launch_bounds__(256) void k_rows_fwd(
    const float* __restrict__ y, float2* __restrict__ zh1, int pairBase) {
  __shared__ float ere[4][EXSZ], eim[4][EXSZ];
  __shared__ float2 tw[512];
  int t = threadIdx.x;
  int w = __builtin_amdgcn_readfirstlane(t >> 6);
  int j = t & 63;
  fill_tw(tw, t);
  __syncthreads();
  int p = blockIdx.x >> 5, bg = blockIdx.x & 31;
  int gp = pairBase + p;
  const float* baseA = y + (size_t)(2 * gp) * IMG_PIX;
  const float* baseB = baseA + IMG_PIX;
  float2* plA = zh1 + (size_t)(2 * p) * PLANE;   // chunk-local planes
  float2* plB = plA + PLANE;
  for (int q = 0; q < 4; ++q) {
    int row = bg * 16 + q * 4 + w;
    const float* rA = baseA + (size_t)row * FFT_N;
    const float* rB = baseB + (size_t)row * FFT_N;
    float2 r[8];
    #pragma unroll
    for (int a = 0; a < 8; ++a) r[a] = make_float2(rA[64 * a + j], rB[64 * a + j]);
    fft512_reg<false>(r, ere[w], eim[w], tw, j);
    bitswap_lanes(r, j);                 // lane j reg f  <->  Z[64f + j]
    float2 m[8];
    int msrc = (64 - j) & 63;
    #pragma unroll
    for (int f = 0; f < 8; ++f) { m[f].x = __shfl(r[f].x, msrc); m[f].y = __shfl(r[f].y, msrc); }
    float2* wA = plA + (size_t)row * NV;
    float2* wB = plB + (size_t)row * NV;
    #pragma unroll
    for (int f = 0; f < 5; ++f) {
      int v = 64 * f + j;
      float2 Zp = r[f];
      float2 Zm = (j == 0) ? m[(8 - f) & 7] : m[7 - f];   // Z[(512 - v) & 511]
      float2 ya = make_float2(0.5f * (Zp.x + Zm.x), 0.5f * (Zp.y - Zm.y));
      float2 yb = make_float2(0.5f * (Zp.y + Zm.y), 0.5f * (Zm.x - Zp.x));
      if (v <= 256) { wA[v] = ya; wB[v] = yb; }
    }
  }
}

// Tiled plane transpose: src[H][W] -> dst[W][H], one plane per blockIdx.z.
__global__ __launch_bounds__(256) void k_transpose(
    const float2* __restrict__ src, float2* __restrict__ dst, int H, int W) {
  __shared__ float2 tile[32][33];
  size_t po = (size_t)blockIdx.z * H * W;
  const float2* s = src + po;
  float2* d = dst + po;
  int tx = threadIdx.x & 31, ty = threadIdx.x >> 5;
  int w0 = blockIdx.x * 32, h0 = blockIdx.y * 32;
  #pragma unroll
  for (int k = 0; k < 4; ++k) {
    int h = h0 + ty + 8 * k, ww = w0 + tx;
    if (h < H && ww < W) tile[ty + 8 * k][tx] = s[(size_t)h * W + ww];
  }
  __syncthreads();
  #pragma unroll
  for (int k = 0; k < 4; ++k) {
    int wr = w0 + ty + 8 * k, hr = h0 + tx;
    if (wr < W && hr < H) d[(size_t)wr * H + hr] = tile[tx][ty + 8 * k];
  }
}

// Fused per-image column pass: fwd FFT + Wiener + inv FFT, on zh2[img][v][row]
// (columns contiguous). One wave per column, in place. Final 1/N^2 folded in.
__global__ __launch_bounds__(256, 4) void k_col_wiener(
    float2* __restrict__ zh2, const float2* __restrict__ St, int imgBase) {
  __shared__ float ere[4][EXSZ], eim[4][EXSZ];
  __shared__ float2 tw[512];
  int t = threadIdx.x;
  int w = __builtin_amdgcn_readfirstlane(t >> 6);
  int j = t & 63;
  fill_tw(tw, t);
  __syncthreads();
  int img_l = blockIdx.x / 17, vg = blockIdx.x % 17;
  int img = imgBase + img_l;
  const float SC = 1.f / (float)IMG_PIX;
  for (int q = 0; q < 4; ++q) {
    int v = vg * 16 + w * 4 + q;               // wave-uniform
    bool ok = (v <= 256);
    float2* col = zh2 + ((size_t)img_l * NV + (ok ? v : 0)) * FFT_N;
    float2 r[8];
    #pragma unroll
    for (int a = 0; a < 8; ++a) r[a] = ok ? col[64 * a + j] : make_float2(0.f, 0.f);
    fft512_reg<false>(r, ere[w], eim[w], tw, j);
    if (ok) {
      const float2* sp = St + ((size_t)img * NV + v) * KSZ;   // uniform -> s_load
      float2 sv[KSZ];
      #pragma unroll
      for (int i = 0; i < KSZ; ++i) sv[i] = sp[i];
      float lv = 2.f - 2.f * tw[v].x;
      int u0 = (j >> 3) + 8 * (j & 7);          // fwd-output layout: u = u0+64f
      #pragma unroll
      for (int f = 0; f < 8; ++f) {
        int u = u0 + 64 * f;
        float2 wu = tw[u];
        float2 c7 = tw[(7 * u) & 511];
        float2 cu = make_float2(c7.x, -c7.y);   // e^{+2pi i 7u/512}
        float2 H = make_float2(0.f, 0.f);
        #pragma unroll
        for (int i = 0; i < KSZ; ++i) {
          H.x += cu.x * sv[i].x - cu.y * sv[i].y;
          H.y += cu.x * sv[i].y + cu.y * sv[i].x;
          cu = cmul(cu, wu);
        }
        float lap = (2.f - 2.f * wu.x) + lv;
        float inv = SC / (H.x * H.x + H.y * H.y + BAL * lap * lap);
        float2 Z = r[f];
        r[f] = make_float2((H.x * Z.x + H.y * Z.y) * inv,
                           (H.x * Z.y - H.y * Z.x) * inv);
      }
    }
    bitswap_lanes(r, j);                  // -> lane-linear k for the inverse
    fft512_reg<true>(r, ere[w], eim[w], tw, j);
    bitswap_lanes(r, j);                  // -> lane-linear pixels
    if (ok) {
      #pragma unroll
      for (int f = 0; f < 8; ++f) col[64 * f + j] = r[f];
    }
  }
}

// Hermitian repack + inverse row FFT + clip/store both images (scale already
// folded into the Wiener multiply).
__global__ __launch_bounds__(256) void k_rows_inv(
    const float2* __restrict__ zh1, float* __restrict__ out, int pairBase) {
  __shared__ float ere[4][EXSZ], eim[4][EXSZ];
  __shared__ float2 tw[512];
  int t = threadIdx.x;
  int w = __builtin_amdgcn_readfirstlane(t >> 6);
  int j = t & 63;
  fill_tw(tw, t);
  __syncthreads();
  int p = blockIdx.x >> 5, bg = blockIdx.x & 31;
  int gp = pairBase + p;
  const float2* plA = zh1 + (size_t)(2 * p) * PLANE;
  const float2* plB = plA + PLANE;
  float* baseA = out + (size_t)(2 * gp) * IMG_PIX;
  float* baseB = baseA + IMG_PIX;
  for (int q = 0; q < 4; ++q) {
    int row = bg * 16 + q * 4 + w;
    const float2* rA = plA + (size_t)row * NV;
    const float2* rB = plB + (size_t)row * NV;
    float2 r[8];
    #pragma unroll
    for (int a = 0; a < 8; ++a) {
      int n = 64 * a + j;
      if (n <= 256) {
        float2 ya = rA[n], yb = rB[n];
        r[a] = make_float2(ya.x - yb.y, ya.y + yb.x);        // YA + i YB
      } else {
        int n2 = 512 - n;
        float2 ya = rA[n2], yb = rB[n2];
        r[a] = make_float2(ya.x + yb.y, yb.x - ya.y);        // conj(YA)+i conj(YB)
      }
    }
    fft512_reg<true>(r, ere[w], eim[w], tw, j);
    bitswap_lanes(r, j);                  // lane j reg f <-> pixel 64f + j
    float* oA = baseA + (size_t)row * FFT_N;
    float* oB = baseB + (size_t)row * FFT_N;
    #pragma unroll
    for (int f = 0; f < 8; ++f) {
      int px = 64 * f + j;
      oA[px] = fminf(1.f, fmaxf(-1.f, r[f].x));
      oB[px] = fminf(1.f, fmaxf(-1.f, r[f].y));
    }
  }
}

extern "C" void kernel_launch(void* const* d_in, const int* in_sizes, int n_in,
                              void* d_out, int out_size, void* d_ws, size_t ws_size,
                              hipStream_t stream) {
  const float* y       = (const float*)d_in[0];
  const float* filters = (const float*)d_in[1];
  float* out = (float*)d_out;

  // ws: [St: 48*257*15 f2 = 1.48MB][zh1: chunk*2 planes][zh2: chunk*2 planes]
  size_t sElems = (size_t)NIMG * NV * KSZ;
  float2* St = (float2*)d_ws;
  size_t sBytes = sElems * sizeof(float2);
  size_t zBytes = (ws_size > sBytes) ? (ws_size - sBytes) : 0;
  size_t perPair = 4 * PLANE * sizeof(float2);   // zh1+zh2, 2 planes each
  int chunk = (int)(zBytes / perPair);
  if (chunk > NPAIR) chunk = NPAIR;
  if (chunk < 1)     chunk = 1;
  float2* zh1 = St + sElems;
  float2* zh2 = zh1 + (size_t)chunk * 2 * PLANE;

  k_psf<<<NIMG, 256, 0, stream>>>(filters, St);

  for (int p0 = 0; p0 < NPAIR; p0 += chunk) {
    int nc = (chunk < NPAIR - p0) ? chunk : (NPAIR - p0);
    k_rows_fwd  <<<nc * 32, 256, 0, stream>>>(y, zh1, p0);
    k_transpose <<<dim3(9, 16, 2 * nc), 256, 0, stream>>>(zh1, zh2, FFT_N, NV);
    k_col_wiener<<<2 * nc * 17, 256, 0, stream>>>(zh2, St, 2 * p0);
    k_transpose <<<dim3(16, 9, 2 * nc), 256, 0, stream>>>(zh2, zh1, NV, FFT_N);
    k_rows_inv  <<<nc * 32, 256, 0, stream>>>(zh1, out, p0);
  }
}

// Round 6
// 195.324 us; speedup vs baseline: 1.5083x; 1.5083x over previous
//
#include <hip/hip_runtime.h>
#include <cstddef>
#include <cmath>

#define FFT_N    512
#define IMG_PIX  (FFT_N * FFT_N)
#define NIMG     48          // B*C
#define NPAIR    24
#define KSZ      15
#define KK       (KSZ * KSZ)
#define BAL      0.1f
#define TWO_PI   6.283185307179586f
#define NV       257                         // rfft half-width (v = 0..256)
#define PLANE    ((size_t)FFT_N * NV)        // elems per image half-spectrum plane
#define EXSZ     576                         // per-wave exchange buffer (floats)

__device__ __forceinline__ float2 cadd(float2 a, float2 b) { return make_float2(a.x + b.x, a.y + b.y); }
__device__ __forceinline__ float2 csub(float2 a, float2 b) { return make_float2(a.x - b.x, a.y - b.y); }
__device__ __forceinline__ float2 cmul(float2 a, float2 b) {
  return make_float2(a.x * b.x - a.y * b.y, a.x * b.y + a.y * b.x);
}
__device__ __forceinline__ int ex1(int c, int b, int g) { return 72 * c + 8 * b + g; }
__device__ __forceinline__ int ex2(int c, int e, int g) { return 72 * c + 9 * e + g; }

// Wave-local ordering fence: exchange buffers are wave-private and DS ops from
// one wave complete in order, so no block barrier is needed — only a compiler
// fence so LDS reads/writes are not reordered across the exchange phases.
__device__ __forceinline__ void wsync() {
  asm volatile("" ::: "memory");
  __builtin_amdgcn_wave_barrier();
  asm volatile("" ::: "memory");
}

// DFT8 over the 8 registers: out[k] = sum_a in[a] e^{-+2pi i a k/8} (INV => +).
template <bool INV>
__device__ __forceinline__ void dft8(float2 r[8]) {
  const float RH = 0.70710678118654752440f;
  float2 s0 = cadd(r[0], r[4]), s1 = cadd(r[1], r[5]), s2 = cadd(r[2], r[6]), s3 = cadd(r[3], r[7]);
  float2 d0 = csub(r[0], r[4]), d1 = csub(r[1], r[5]), d2 = csub(r[2], r[6]), d3 = csub(r[3], r[7]);
  if (!INV) {
    d1 = make_float2(RH * (d1.x + d1.y), RH * (d1.y - d1.x));   // *W8^1
    d2 = make_float2(d2.y, -d2.x);                              // *-i
    d3 = make_float2(RH * (d3.y - d3.x), RH * (-d3.x - d3.y));  // *W8^3
  } else {
    d1 = make_float2(RH * (d1.x - d1.y), RH * (d1.x + d1.y));   // *W8^-1
    d2 = make_float2(-d2.y, d2.x);                              // *+i
    d3 = make_float2(RH * (-d3.x - d3.y), RH * (d3.x - d3.y));  // *W8^-3
  }
  float2 t0 = cadd(s0, s2), t1 = csub(s0, s2), t2 = cadd(s1, s3), t3 = csub(s1, s3);
  t3 = INV ? make_float2(-t3.y, t3.x) : make_float2(t3.y, -t3.x);
  float2 E0 = cadd(t0, t2), E1 = cadd(t1, t3), E2 = csub(t0, t2), E3 = csub(t1, t3);
  t0 = cadd(d0, d2); t1 = csub(d0, d2); t2 = cadd(d1, d3); t3 = csub(d1, d3);
  t3 = INV ? make_float2(-t3.y, t3.x) : make_float2(t3.y, -t3.x);
  r[0] = E0; r[2] = E1; r[4] = E2; r[6] = E3;
  r[1] = cadd(t0, t2); r[3] = cadd(t1, t3); r[5] = csub(t0, t2); r[7] = csub(t1, t3);
}

// 512-pt FFT, one wave per line, data in 8 regs. tw[k] = e^{-2pi i k/512}.
// Forward: input r[a] = x[64a + j] -> lane 8c+e, reg f holds X[c + 8e + 64f]
// (bitswap-lanes => lane-linear). Inverse: conjugate graph, same geometry.
template <bool INV>
__device__ void fft512_reg(float2 r[8], float* ere, float* eim, const float2* tw, int j) {
  const int hi = j >> 3, lo = j & 7;
  dft8<INV>(r);                         // over a -> regs c
  #pragma unroll
  for (int c = 1; c < 8; ++c) {         // twiddle W64^{b c}
    float2 w = tw[(8 * hi * c) & 511];
    if (INV) w.y = -w.y;
    r[c] = cmul(r[c], w);
  }
  #pragma unroll
  for (int c = 0; c < 8; ++c) { int a = ex1(c, hi, lo); ere[a] = r[c].x; eim[a] = r[c].y; }
  wsync();
  #pragma unroll
  for (int b = 0; b < 8; ++b) { int a = ex1(hi, b, lo); r[b] = make_float2(ere[a], eim[a]); }
  dft8<INV>(r);                         // over b -> regs e
  {                                     // twiddle W512^{g(c+8e)} via recurrence
    float2 base = tw[(lo * hi) & 511];
    float2 step = tw[(8 * lo) & 511];
    if (INV) { base.y = -base.y; step.y = -step.y; }
    #pragma unroll
    for (int e = 0; e < 8; ++e) { r[e] = cmul(r[e], base); base = cmul(base, step); }
  }
  wsync();                              // ex1 reads must precede ex2 writes
  #pragma unroll
  for (int e = 0; e < 8; ++e) { int a = ex2(hi, e, lo); ere[a] = r[e].x; eim[a] = r[e].y; }
  wsync();
  #pragma unroll
  for (int g = 0; g < 8; ++g) { int a = ex2(hi, lo, g); r[g] = make_float2(ere[a], eim[a]); }
  dft8<INV>(r);                         // over g -> regs f
}

// lane bit-swap (hi3<->lo3): converts (c,e)-lane layout <-> lane-linear layout.
__device__ __forceinline__ void bitswap_lanes(float2 r[8], int j) {
  int src = ((j & 7) << 3) | (j >> 3);
  #pragma unroll
  for (int f = 0; f < 8; ++f) {
    r[f].x = __shfl(r[f].x, src);
    r[f].y = __shfl(r[f].y, src);
  }
}

__device__ __forceinline__ void fill_tw(float2* tw, int t) {
  float s, c;
  float ang = -TWO_PI * (float)t / (float)FFT_N;
  sincosf(ang, &s, &c); tw[t] = make_float2(c, s);
  ang = -TWO_PI * (float)(t + 256) / (float)FFT_N;
  sincosf(ang, &s, &c); tw[t + 256] = make_float2(c, s);
}

// PSF row-DFT, transposed: St[img][v][i] = sum_j f[i][j] e^{-2pi i v(j-7)/512},
// v in [0,256]. Contiguous 15-float2 run per (img,v).
__global__ __launch_bounds__(256) void k_psf(
    const float* __restrict__ filters, float2* __restrict__ St) {
  __shared__ float fs[KK];
  int img = blockIdx.x;
  int t = threadIdx.x;
  if (t < KK) fs[t] = filters[(size_t)img * KK + t];
  __syncthreads();
  for (int v = t; v < NV; v += 256) {
    float cs[KSZ], sn[KSZ];
    #pragma unroll
    for (int jj = 0; jj < KSZ; ++jj) {
      float ang = -TWO_PI * (float)(v * (jj - 7)) / (float)FFT_N;
      sincosf(ang, &sn[jj], &cs[jj]);
    }
    float2* dst = St + ((size_t)img * NV + v) * KSZ;
    #pragma unroll
    for (int i = 0; i < KSZ; ++i) {
      float2 s = make_float2(0.f, 0.f);
      #pragma unroll
      for (int jj = 0; jj < KSZ; ++jj) {
        float fv = fs[i * KSZ + jj];
        s.x += fv * cs[jj];
        s.y += fv * sn[jj];
      }
      dst[i] = s;
    }
  }
}

// Row FFT of packed pair (z = yA + i yB) + Hermitian unpack; writes per-image
// half-spectrum planes zh1[img][row][v], v in [0,256]. One wave per row.
__global__ __launch_bounds__(256) void k_rows_fwd(
    const float* __restrict__ y, float2* __restrict__ zh1, int pairBase) {
  __shared__ float ere[4][EXSZ], eim[4][EXSZ];
  __shared__ float2 tw[512];
  int t = threadIdx.x;
  int w = __builtin_amdgcn_readfirstlane(t >> 6);
  int j = t & 63;
  fill_tw(tw, t);
  __syncthreads();
  int p = blockIdx.x >> 5, bg = blockIdx.x & 31;
  int gp = pairBase + p;
  const float* baseA = y + (size_t)(2 * gp) * IMG_PIX;
  const float* baseB = baseA + IMG_PIX;
  float2* plA = zh1 + (size_t)(2 * p) * PLANE;   // chunk-local planes
  float2* plB = plA + PLANE;
  for (int q = 0; q < 4; ++q) {
    int row = bg * 16 + q * 4 + w;
    const float* rA = baseA + (size_t)row * FFT_N;
    const float* rB = baseB + (size_t)row * FFT_N;
    float2 r[8];
    #pragma unroll
    for (int a = 0; a < 8; ++a) r[a] = make_float2(rA[64 * a + j], rB[64 * a + j]);
    fft512_reg<false>(r, ere[w], eim[w], tw, j);
    bitswap_lanes(r, j);                 // lane j reg f  <->  Z[64f + j]
    float2 m[8];
    int msrc = (64 - j) & 63;
    #pragma unroll
    for (int f = 0; f < 8; ++f) { m[f].x = __shfl(r[f].x, msrc); m[f].y = __shfl(r[f].y, msrc); }
    float2* wA = plA + (size_t)row * NV;
    float2* wB = plB + (size_t)row * NV;
    #pragma unroll
    for (int f = 0; f < 5; ++f) {
      int v = 64 * f + j;
      float2 Zp = r[f];
      float2 Zm = (j == 0) ? m[(8 - f) & 7] : m[7 - f];   // Z[(512 - v) & 511]
      float2 ya = make_float2(0.5f * (Zp.x + Zm.x), 0.5f * (Zp.y - Zm.y));
      float2 yb = make_float2(0.5f * (Zp.y + Zm.y), 0.5f * (Zm.x - Zp.x));
      if (v <= 256) { wA[v] = ya; wB[v] = yb; }
    }
  }
}

// Tiled plane transpose: src[H][W] -> dst[W][H], one plane per blockIdx.z.
__global__ __launch_bounds__(256) void k_transpose(
    const float2* __restrict__ src, float2* __restrict__ dst, int H, int W) {
  __shared__ float2 tile[32][33];
  size_t po = (size_t)blockIdx.z * H * W;
  const float2* s = src + po;
  float2* d = dst + po;
  int tx = threadIdx.x & 31, ty = threadIdx.x >> 5;
  int w0 = blockIdx.x * 32, h0 = blockIdx.y * 32;
  #pragma unroll
  for (int k = 0; k < 4; ++k) {
    int h = h0 + ty + 8 * k, ww = w0 + tx;
    if (h < H && ww < W) tile[ty + 8 * k][tx] = s[(size_t)h * W + ww];
  }
  __syncthreads();
  #pragma unroll
  for (int k = 0; k < 4; ++k) {
    int wr = w0 + ty + 8 * k, hr = h0 + tx;
    if (wr < W && hr < H) d[(size_t)wr * H + hr] = tile[tx][ty + 8 * k];
  }
}

// Fused per-image column pass: fwd FFT + Wiener + inv FFT, on zh2[img][v][row]
// (columns contiguous). One wave per column, in place. Final 1/N^2 folded in.
// Wiener H for all 8 u-values (u = u0 + 64f) comes from one DFT8:
//   H(u0+64f) = sum_i St[i] e^{-2pi i u0(i-7)/512} * W8^{f((i-7) mod 8)}
__global__ __launch_bounds__(256) void k_col_wiener(
    float2* __restrict__ zh2, const float2* __restrict__ St, int imgBase) {
  __shared__ float ere[4][EXSZ], eim[4][EXSZ];
  __shared__ float2 tw[512];
  int t = threadIdx.x;
  int w = __builtin_amdgcn_readfirstlane(t >> 6);
  int j = t & 63;
  fill_tw(tw, t);
  __syncthreads();
  int img_l = blockIdx.x / 17, vg = blockIdx.x % 17;
  int img = imgBase + img_l;
  const float SC = 1.f / (float)IMG_PIX;
  for (int q = 0; q < 4; ++q) {
    int v = vg * 16 + w * 4 + q;               // wave-uniform
    bool ok = (v <= 256);
    float2* col = zh2 + ((size_t)img_l * NV + (ok ? v : 0)) * FFT_N;
    float2 r[8];
    #pragma unroll
    for (int a = 0; a < 8; ++a) r[a] = ok ? col[64 * a + j] : make_float2(0.f, 0.f);
    fft512_reg<false>(r, ere[w], eim[w], tw, j);
    if (ok) {
      const float2* sp = St + ((size_t)img * NV + v) * KSZ;
      int u0 = (j >> 3) + 8 * (j & 7);          // fwd-output layout: u = u0+64f
      float2 G[8];
      #pragma unroll
      for (int m = 0; m < 8; ++m) G[m] = make_float2(0.f, 0.f);
      #pragma unroll
      for (int i = 0; i < KSZ; ++i) {
        float2 wb = tw[(u0 * (i - 7)) & 511];   // e^{-2pi i u0(i-7)/512}
        float2 b = cmul(sp[i], wb);
        int m = (i + 1) & 7;                    // (i-7) mod 8
        G[m] = cadd(G[m], b);
      }
      dft8<false>(G);                           // G[f] = H(u0 + 64f)
      float lv = 2.f - 2.f * tw[v].x;
      #pragma unroll
      for (int f = 0; f < 8; ++f) {
        int u = u0 + 64 * f;
        float2 H = G[f];
        float lap = (2.f - 2.f * tw[u].x) + lv;
        float inv = SC / (H.x * H.x + H.y * H.y + BAL * lap * lap);
        float2 Z = r[f];
        r[f] = make_float2((H.x * Z.x + H.y * Z.y) * inv,
                           (H.x * Z.y - H.y * Z.x) * inv);
      }
    }
    bitswap_lanes(r, j);                  // -> lane-linear k for the inverse
    fft512_reg<true>(r, ere[w], eim[w], tw, j);
    bitswap_lanes(r, j);                  // -> lane-linear pixels
    if (ok) {
      #pragma unroll
      for (int f = 0; f < 8; ++f) col[64 * f + j] = r[f];
    }
  }
}

// Hermitian repack + inverse row FFT + clip/store both images (scale already
// folded into the Wiener multiply).
__global__ __launch_bounds__(256) void k_rows_inv(
    const float2* __restrict__ zh1, float* __restrict__ out, int pairBase) {
  __shared__ float ere[4][EXSZ], eim[4][EXSZ];
  __shared__ float2 tw[512];
  int t = threadIdx.x;
  int w = __builtin_amdgcn_readfirstlane(t >> 6);
  int j = t & 63;
  fill_tw(tw, t);
  __syncthreads();
  int p = blockIdx.x >> 5, bg = blockIdx.x & 31;
  int gp = pairBase + p;
  const float2* plA = zh1 + (size_t)(2 * p) * PLANE;
  const float2* plB = plA + PLANE;
  float* baseA = out + (size_t)(2 * gp) * IMG_PIX;
  float* baseB = baseA + IMG_PIX;
  for (int q = 0; q < 4; ++q) {
    int row = bg * 16 + q * 4 + w;
    const float2* rA = plA + (size_t)row * NV;
    const float2* rB = plB + (size_t)row * NV;
    float2 r[8];
    #pragma unroll
    for (int a = 0; a < 8; ++a) {
      int n = 64 * a + j;
      if (n <= 256) {
        float2 ya = rA[n], yb = rB[n];
        r[a] = make_float2(ya.x - yb.y, ya.y + yb.x);        // YA + i YB
      } else {
        int n2 = 512 - n;
        float2 ya = rA[n2], yb = rB[n2];
        r[a] = make_float2(ya.x + yb.y, yb.x - ya.y);        // conj(YA)+i conj(YB)
      }
    }
    fft512_reg<true>(r, ere[w], eim[w], tw, j);
    bitswap_lanes(r, j);                  // lane j reg f <-> pixel 64f + j
    float* oA = baseA + (size_t)row * FFT_N;
    float* oB = baseB + (size_t)row * FFT_N;
    #pragma unroll
    for (int f = 0; f < 8; ++f) {
      int px = 64 * f + j;
      oA[px] = fminf(1.f, fmaxf(-1.f, r[f].x));
      oB[px] = fminf(1.f, fmaxf(-1.f, r[f].y));
    }
  }
}

extern "C" void kernel_launch(void* const* d_in, const int* in_sizes, int n_in,
                              void* d_out, int out_size, void* d_ws, size_t ws_size,
                              hipStream_t stream) {
  const float* y       = (const float*)d_in[0];
  const float* filters = (const float*)d_in[1];
  float* out = (float*)d_out;

  // ws: [St: 48*257*15 f2 = 1.48MB][zh1: chunk*2 planes][zh2: chunk*2 planes]
  size_t sElems = (size_t)NIMG * NV * KSZ;
  float2* St = (float2*)d_ws;
  size_t sBytes = sElems * sizeof(float2);
  size_t zBytes = (ws_size > sBytes) ? (ws_size - sBytes) : 0;
  size_t perPair = 4 * PLANE * sizeof(float2);   // zh1+zh2, 2 planes each
  int chunk = (int)(zBytes / perPair);
  if (chunk > NPAIR) chunk = NPAIR;
  if (chunk < 1)     chunk = 1;
  float2* zh1 = St + sElems;
  float2* zh2 = zh1 + (size_t)chunk * 2 * PLANE;

  k_psf<<<NIMG, 256, 0, stream>>>(filters, St);

  for (int p0 = 0; p0 < NPAIR; p0 += chunk) {
    int nc = (chunk < NPAIR - p0) ? chunk : (NPAIR - p0);
    k_rows_fwd  <<<nc * 32, 256, 0, stream>>>(y, zh1, p0);
    k_transpose <<<dim3(9, 16, 2 * nc), 256, 0, stream>>>(zh1, zh2, FFT_N, NV);
    k_col_wiener<<<2 * nc * 17, 256, 0, stream>>>(zh2, St, 2 * p0);
    k_transpose <<<dim3(16, 9, 2 * nc), 256, 0, stream>>>(zh2, zh1, NV, FFT_N);
    k_rows_inv  <<<nc * 32, 256, 0, stream>>>(zh1, out, p0);
  }
}

// Round 7
// 173.105 us; speedup vs baseline: 1.7019x; 1.1284x over previous
//
#include <hip/hip_runtime.h>
#include <cstddef>
#include <cmath>

#define FFT_N    512
#define IMG_PIX  (FFT_N * FFT_N)
#define NIMG     48          // B*C
#define NPAIR    24
#define KSZ      15
#define KK       (KSZ * KSZ)
#define BAL      0.1f
#define TWO_PI   6.283185307179586f
#define NV       257                         // rfft half-width (v = 0..256)
#define RS       264                         // padded plane row stride (float2), 64B-aligned
#define PLANE    ((size_t)FFT_N * RS)        // elems per image half-spectrum plane
#define EXSZ     576                         // per-wave exchange buffer (floats)

__device__ __forceinline__ float2 cadd(float2 a, float2 b) { return make_float2(a.x + b.x, a.y + b.y); }
__device__ __forceinline__ float2 csub(float2 a, float2 b) { return make_float2(a.x - b.x, a.y - b.y); }
__device__ __forceinline__ float2 cmul(float2 a, float2 b) {
  return make_float2(a.x * b.x - a.y * b.y, a.x * b.y + a.y * b.x);
}
__device__ __forceinline__ int ex1(int c, int b, int g) { return 72 * c + 8 * b + g; }
__device__ __forceinline__ int ex2(int c, int e, int g) { return 72 * c + 9 * e + g; }

// Wave-local ordering fence (exchange buffers are wave-private).
__device__ __forceinline__ void wsync() {
  asm volatile("" ::: "memory");
  __builtin_amdgcn_wave_barrier();
  asm volatile("" ::: "memory");
}

// DFT8 over the 8 registers: out[k] = sum_a in[a] e^{-+2pi i a k/8} (INV => +).
template <bool INV>
__device__ __forceinline__ void dft8(float2 r[8]) {
  const float RH = 0.70710678118654752440f;
  float2 s0 = cadd(r[0], r[4]), s1 = cadd(r[1], r[5]), s2 = cadd(r[2], r[6]), s3 = cadd(r[3], r[7]);
  float2 d0 = csub(r[0], r[4]), d1 = csub(r[1], r[5]), d2 = csub(r[2], r[6]), d3 = csub(r[3], r[7]);
  if (!INV) {
    d1 = make_float2(RH * (d1.x + d1.y), RH * (d1.y - d1.x));   // *W8^1
    d2 = make_float2(d2.y, -d2.x);                              // *-i
    d3 = make_float2(RH * (d3.y - d3.x), RH * (-d3.x - d3.y));  // *W8^3
  } else {
    d1 = make_float2(RH * (d1.x - d1.y), RH * (d1.x + d1.y));   // *W8^-1
    d2 = make_float2(-d2.y, d2.x);                              // *+i
    d3 = make_float2(RH * (-d3.x - d3.y), RH * (d3.x - d3.y));  // *W8^-3
  }
  float2 t0 = cadd(s0, s2), t1 = csub(s0, s2), t2 = cadd(s1, s3), t3 = csub(s1, s3);
  t3 = INV ? make_float2(-t3.y, t3.x) : make_float2(t3.y, -t3.x);
  float2 E0 = cadd(t0, t2), E1 = cadd(t1, t3), E2 = csub(t0, t2), E3 = csub(t1, t3);
  t0 = cadd(d0, d2); t1 = csub(d0, d2); t2 = cadd(d1, d3); t3 = csub(d1, d3);
  t3 = INV ? make_float2(-t3.y, t3.x) : make_float2(t3.y, -t3.x);
  r[0] = E0; r[2] = E1; r[4] = E2; r[6] = E3;
  r[1] = cadd(t0, t2); r[3] = cadd(t1, t3); r[5] = csub(t0, t2); r[7] = csub(t1, t3);
}

// 512-pt FFT, one wave per line, data in 8 regs. tw[k] = e^{-2pi i k/512}.
// Forward: input r[a] = x[64a + j] -> lane 8c+e, reg f holds X[c + 8e + 64f]
// (bitswap-lanes => lane-linear). Inverse: conjugate graph, same geometry.
template <bool INV>
__device__ void fft512_reg(float2 r[8], float* ere, float* eim, const float2* tw, int j) {
  const int hi = j >> 3, lo = j & 7;
  dft8<INV>(r);                         // over a -> regs c
  #pragma unroll
  for (int c = 1; c < 8; ++c) {         // twiddle W64^{b c}
    float2 w = tw[(8 * hi * c) & 511];
    if (INV) w.y = -w.y;
    r[c] = cmul(r[c], w);
  }
  #pragma unroll
  for (int c = 0; c < 8; ++c) { int a = ex1(c, hi, lo); ere[a] = r[c].x; eim[a] = r[c].y; }
  wsync();
  #pragma unroll
  for (int b = 0; b < 8; ++b) { int a = ex1(hi, b, lo); r[b] = make_float2(ere[a], eim[a]); }
  dft8<INV>(r);                         // over b -> regs e
  {                                     // twiddle W512^{g(c+8e)} via recurrence
    float2 base = tw[(lo * hi) & 511];
    float2 step = tw[(8 * lo) & 511];
    if (INV) { base.y = -base.y; step.y = -step.y; }
    #pragma unroll
    for (int e = 0; e < 8; ++e) { r[e] = cmul(r[e], base); base = cmul(base, step); }
  }
  wsync();                              // ex1 reads must precede ex2 writes
  #pragma unroll
  for (int e = 0; e < 8; ++e) { int a = ex2(hi, e, lo); ere[a] = r[e].x; eim[a] = r[e].y; }
  wsync();
  #pragma unroll
  for (int g = 0; g < 8; ++g) { int a = ex2(hi, lo, g); r[g] = make_float2(ere[a], eim[a]); }
  dft8<INV>(r);                         // over g -> regs f
}

// lane bit-swap (hi3<->lo3): converts (c,e)-lane layout <-> lane-linear layout.
__device__ __forceinline__ void bitswap_lanes(float2 r[8], int j) {
  int src = ((j & 7) << 3) | (j >> 3);
  #pragma unroll
  for (int f = 0; f < 8; ++f) {
    r[f].x = __shfl(r[f].x, src);
    r[f].y = __shfl(r[f].y, src);
  }
}

__device__ __forceinline__ void fill_tw(float2* tw, int t) {
  float s, c;
  float ang = -TWO_PI * (float)t / (float)FFT_N;
  sincosf(ang, &s, &c); tw[t] = make_float2(c, s);
  ang = -TWO_PI * (float)(t + 256) / (float)FFT_N;
  sincosf(ang, &s, &c); tw[t + 256] = make_float2(c, s);
}

// PSF row-DFT, transposed: St[img][v][i] = sum_j f[i][j] e^{-2pi i v(j-7)/512},
// v in [0,256]. Contiguous 15-float2 run per (img,v).
__global__ __launch_bounds__(256) void k_psf(
    const float* __restrict__ filters, float2* __restrict__ St) {
  __shared__ float fs[KK];
  int img = blockIdx.x;
  int t = threadIdx.x;
  if (t < KK) fs[t] = filters[(size_t)img * KK + t];
  __syncthreads();
  for (int v = t; v < NV; v += 256) {
    float cs[KSZ], sn[KSZ];
    #pragma unroll
    for (int jj = 0; jj < KSZ; ++jj) {
      float ang = -TWO_PI * (float)(v * (jj - 7)) / (float)FFT_N;
      sincosf(ang, &sn[jj], &cs[jj]);
    }
    float2* dst = St + ((size_t)img * NV + v) * KSZ;
    #pragma unroll
    for (int i = 0; i < KSZ; ++i) {
      float2 s = make_float2(0.f, 0.f);
      #pragma unroll
      for (int jj = 0; jj < KSZ; ++jj) {
        float fv = fs[i * KSZ + jj];
        s.x += fv * cs[jj];
        s.y += fv * sn[jj];
      }
      dst[i] = s;
    }
  }
}

// Row FFT of packed pair (z = yA + i yB) + Hermitian unpack; writes per-image
// half-spectrum planes zh[img][row][v] (row stride RS). One wave per row.
__global__ __launch_bounds__(256) void k_rows_fwd(
    const float* __restrict__ y, float2* __restrict__ zh, int pairBase) {
  __shared__ float ere[4][EXSZ], eim[4][EXSZ];
  __shared__ float2 tw[512];
  int t = threadIdx.x;
  int w = __builtin_amdgcn_readfirstlane(t >> 6);
  int j = t & 63;
  fill_tw(tw, t);
  __syncthreads();
  int p = blockIdx.x >> 5, bg = blockIdx.x & 31;
  int gp = pairBase + p;
  const float* baseA = y + (size_t)(2 * gp) * IMG_PIX;
  const float* baseB = baseA + IMG_PIX;
  float2* plA = zh + (size_t)(2 * p) * PLANE;   // chunk-local planes
  float2* plB = plA + PLANE;
  for (int q = 0; q < 4; ++q) {
    int row = bg * 16 + q * 4 + w;
    const float* rA = baseA + (size_t)row * FFT_N;
    const float* rB = baseB + (size_t)row * FFT_N;
    float2 r[8];
    #pragma unroll
    for (int a = 0; a < 8; ++a) r[a] = make_float2(rA[64 * a + j], rB[64 * a + j]);
    fft512_reg<false>(r, ere[w], eim[w], tw, j);
    bitswap_lanes(r, j);                 // lane j reg f  <->  Z[64f + j]
    float2 m[8];
    int msrc = (64 - j) & 63;
    #pragma unroll
    for (int f = 0; f < 8; ++f) { m[f].x = __shfl(r[f].x, msrc); m[f].y = __shfl(r[f].y, msrc); }
    float2* wA = plA + (size_t)row * RS;
    float2* wB = plB + (size_t)row * RS;
    #pragma unroll
    for (int f = 0; f < 5; ++f) {
      int v = 64 * f + j;
      float2 Zp = r[f];
      float2 Zm = (j == 0) ? m[(8 - f) & 7] : m[7 - f];   // Z[(512 - v) & 511]
      float2 ya = make_float2(0.5f * (Zp.x + Zm.x), 0.5f * (Zp.y - Zm.y));
      float2 yb = make_float2(0.5f * (Zp.y + Zm.y), 0.5f * (Zm.x - Zp.x));
      if (v <= 256) { wA[v] = ya; wB[v] = yb; }
    }
  }
}

// Fused column pass WITH embedded layout flips: reads 16 columns from the
// row-major plane via LDS-staged 128B-segment gathers, fwd FFT + Wiener +
// inv FFT per column (held in registers), scatters back via LDS. In place.
__global__ __launch_bounds__(256) void k_col_wiener(
    float2* __restrict__ zh, const float2* __restrict__ St, int imgBase) {
  __shared__ float ere[4][EXSZ], eim[4][EXSZ];
  __shared__ float2 tw[512];
  __shared__ float tre[64][17], tim[64][17];   // SoA tile: stride 17 => <=2-way banks
  int t = threadIdx.x;
  int w = __builtin_amdgcn_readfirstlane(t >> 6);
  int j = t & 63;
  fill_tw(tw, t);
  int img_l = blockIdx.x / 17, vg = blockIdx.x % 17;
  int img = imgBase + img_l;
  int vbase = vg * 16;
  int ncols = (vg == 16) ? 1 : 16;
  float2* pl = zh + (size_t)img_l * PLANE;
  const float SC = 1.f / (float)IMG_PIX;
  int vi = t & 15, ri0 = t >> 4;
  float2 rq[4][8];                             // 4 columns x 8 regs, all static idx
  __syncthreads();                             // tw visible
  // ---- gather: 8 row-chunks of [64 rows x ncols]
  #pragma unroll
  for (int a = 0; a < 8; ++a) {
    #pragma unroll
    for (int rr = 0; rr < 4; ++rr) {
      int ri = ri0 + 16 * rr;
      if (vi < ncols) {
        float2 z = pl[(size_t)(64 * a + ri) * RS + vbase + vi];
        tre[ri][vi] = z.x; tim[ri][vi] = z.y;
      }
    }
    __syncthreads();
    #pragma unroll
    for (int q = 0; q < 4; ++q) {
      int c = w * 4 + q;
      int cc = (c < ncols) ? c : 0;
      rq[q][a] = make_float2(tre[j][cc], tim[j][cc]);
    }
    __syncthreads();
  }
  // ---- compute: per-column fwd FFT + Wiener + inv FFT (wave-local only)
  #pragma unroll
  for (int q = 0; q < 4; ++q) {
    int c = w * 4 + q;
    int v = vbase + c;                         // wave-uniform
    bool ok = (v <= 256) && (c < ncols);
    if (ok) {
      fft512_reg<false>(rq[q], ere[w], eim[w], tw, j);
      const float2* sp = St + ((size_t)img * NV + v) * KSZ;
      int u0 = (j >> 3) + 8 * (j & 7);         // fwd-output layout: u = u0+64f
      float2 G[8];
      #pragma unroll
      for (int m = 0; m < 8; ++m) G[m] = make_float2(0.f, 0.f);
      #pragma unroll
      for (int i = 0; i < KSZ; ++i) {
        float2 wb = tw[(u0 * (i - 7)) & 511];  // e^{-2pi i u0(i-7)/512}
        float2 b = cmul(sp[i], wb);
        int m = (i + 1) & 7;                   // (i-7) mod 8
        G[m] = cadd(G[m], b);
      }
      dft8<false>(G);                          // G[f] = H(u0 + 64f)
      float lv = 2.f - 2.f * tw[v].x;
      #pragma unroll
      for (int f = 0; f < 8; ++f) {
        int u = u0 + 64 * f;
        float2 H = G[f];
        float lap = (2.f - 2.f * tw[u].x) + lv;
        float inv = SC / (H.x * H.x + H.y * H.y + BAL * lap * lap);
        float2 Z = rq[q][f];
        rq[q][f] = make_float2((H.x * Z.x + H.y * Z.y) * inv,
                               (H.x * Z.y - H.y * Z.x) * inv);
      }
      bitswap_lanes(rq[q], j);                 // -> lane-linear u for inverse
      fft512_reg<true>(rq[q], ere[w], eim[w], tw, j);
      bitswap_lanes(rq[q], j);                 // -> lane-linear rows: reg f = row 64f+j
    }
  }
  // ---- scatter: 8 row-chunks back to the row-major plane
  #pragma unroll
  for (int f = 0; f < 8; ++f) {
    #pragma unroll
    for (int q = 0; q < 4; ++q) {
      int c = w * 4 + q;
      if (c < ncols && vbase + c <= 256) { tre[j][c] = rq[q][f].x; tim[j][c] = rq[q][f].y; }
    }
    __syncthreads();
    #pragma unroll
    for (int rr = 0; rr < 4; ++rr) {
      int ri = ri0 + 16 * rr;
      if (vi < ncols) {
        pl[(size_t)(64 * f + ri) * RS + vbase + vi] = make_float2(tre[ri][vi], tim[ri][vi]);
      }
    }
    __syncthreads();
  }
}

// Hermitian repack + inverse row FFT + clip/store both images (1/N^2 already
// folded into the Wiener multiply).
__global__ __launch_bounds__(256) void k_rows_inv(
    const float2* __restrict__ zh, float* __restrict__ out, int pairBase) {
  __shared__ float ere[4][EXSZ], eim[4][EXSZ];
  __shared__ float2 tw[512];
  int t = threadIdx.x;
  int w = __builtin_amdgcn_readfirstlane(t >> 6);
  int j = t & 63;
  fill_tw(tw, t);
  __syncthreads();
  int p = blockIdx.x >> 5, bg = blockIdx.x & 31;
  int gp = pairBase + p;
  const float2* plA = zh + (size_t)(2 * p) * PLANE;
  const float2* plB = plA + PLANE;
  float* baseA = out + (size_t)(2 * gp) * IMG_PIX;
  float* baseB = baseA + IMG_PIX;
  for (int q = 0; q < 4; ++q) {
    int row = bg * 16 + q * 4 + w;
    const float2* rA = plA + (size_t)row * RS;
    const float2* rB = plB + (size_t)row * RS;
    float2 r[8];
    #pragma unroll
    for (int a = 0; a < 8; ++a) {
      int n = 64 * a + j;
      if (n <= 256) {
        float2 ya = rA[n], yb = rB[n];
        r[a] = make_float2(ya.x - yb.y, ya.y + yb.x);        // YA + i YB
      } else {
        int n2 = 512 - n;
        float2 ya = rA[n2], yb = rB[n2];
        r[a] = make_float2(ya.x + yb.y, yb.x - ya.y);        // conj(YA)+i conj(YB)
      }
    }
    fft512_reg<true>(r, ere[w], eim[w], tw, j);
    bitswap_lanes(r, j);                  // lane j reg f <-> pixel 64f + j
    float* oA = baseA + (size_t)row * FFT_N;
    float* oB = baseB + (size_t)row * FFT_N;
    #pragma unroll
    for (int f = 0; f < 8; ++f) {
      int px = 64 * f + j;
      oA[px] = fminf(1.f, fmaxf(-1.f, r[f].x));
      oB[px] = fminf(1.f, fmaxf(-1.f, r[f].y));
    }
  }
}

extern "C" void kernel_launch(void* const* d_in, const int* in_sizes, int n_in,
                              void* d_out, int out_size, void* d_ws, size_t ws_size,
                              hipStream_t stream) {
  const float* y       = (const float*)d_in[0];
  const float* filters = (const float*)d_in[1];
  float* out = (float*)d_out;

  // ws: [St: 48*257*15 f2 = 1.48MB][zh: chunk pairs * 2 planes (row stride RS)]
  size_t sElems = (size_t)NIMG * NV * KSZ;
  float2* St = (float2*)d_ws;
  size_t sBytes = sElems * sizeof(float2);
  size_t zBytes = (ws_size > sBytes) ? (ws_size - sBytes) : 0;
  size_t perPair = 2 * PLANE * sizeof(float2);   // ~2.16 MiB
  int chunk = (int)(zBytes / perPair);
  if (chunk > NPAIR) chunk = NPAIR;
  if (chunk < 1)     chunk = 1;
  float2* zh = St + sElems;

  k_psf<<<NIMG, 256, 0, stream>>>(filters, St);

  for (int p0 = 0; p0 < NPAIR; p0 += chunk) {
    int nc = (chunk < NPAIR - p0) ? chunk : (NPAIR - p0);
    k_rows_fwd  <<<nc * 32,     256, 0, stream>>>(y, zh, p0);
    k_col_wiener<<<2 * nc * 17, 256, 0, stream>>>(zh, St, 2 * p0);
    k_rows_inv  <<<nc * 32,     256, 0, stream>>>(zh, out, p0);
  }
}

// Round 8
// 171.534 us; speedup vs baseline: 1.7175x; 1.0092x over previous
//
#include <hip/hip_runtime.h>
#include <cstddef>
#include <cmath>

#define FFT_N    512
#define IMG_PIX  (FFT_N * FFT_N)
#define NIMG     48          // B*C
#define NPAIR    24
#define KSZ      15
#define KK       (KSZ * KSZ)
#define BAL      0.1f
#define TWO_PI   6.283185307179586f
#define NV       257                         // rfft half-width (v = 0..256)
#define RS       264                         // padded plane row stride (float2), 64B-aligned
#define PLANE    ((size_t)FFT_N * RS)        // elems per image half-spectrum plane
#define EXSZ     576                         // per-wave exchange buffer (floats)

__device__ __forceinline__ float2 cadd(float2 a, float2 b) { return make_float2(a.x + b.x, a.y + b.y); }
__device__ __forceinline__ float2 csub(float2 a, float2 b) { return make_float2(a.x - b.x, a.y - b.y); }
__device__ __forceinline__ float2 cmul(float2 a, float2 b) {
  return make_float2(a.x * b.x - a.y * b.y, a.x * b.y + a.y * b.x);
}
__device__ __forceinline__ int ex1(int c, int b, int g) { return 72 * c + 8 * b + g; }
__device__ __forceinline__ int ex2(int c, int e, int g) { return 72 * c + 9 * e + g; }

// Wave-local ordering fence (exchange buffers are wave-private).
__device__ __forceinline__ void wsync() {
  asm volatile("" ::: "memory");
  __builtin_amdgcn_wave_barrier();
  asm volatile("" ::: "memory");
}

// DFT8 over the 8 registers: out[k] = sum_a in[a] e^{-+2pi i a k/8} (INV => +).
template <bool INV>
__device__ __forceinline__ void dft8(float2 r[8]) {
  const float RH = 0.70710678118654752440f;
  float2 s0 = cadd(r[0], r[4]), s1 = cadd(r[1], r[5]), s2 = cadd(r[2], r[6]), s3 = cadd(r[3], r[7]);
  float2 d0 = csub(r[0], r[4]), d1 = csub(r[1], r[5]), d2 = csub(r[2], r[6]), d3 = csub(r[3], r[7]);
  if (!INV) {
    d1 = make_float2(RH * (d1.x + d1.y), RH * (d1.y - d1.x));   // *W8^1
    d2 = make_float2(d2.y, -d2.x);                              // *-i
    d3 = make_float2(RH * (d3.y - d3.x), RH * (-d3.x - d3.y));  // *W8^3
  } else {
    d1 = make_float2(RH * (d1.x - d1.y), RH * (d1.x + d1.y));   // *W8^-1
    d2 = make_float2(-d2.y, d2.x);                              // *+i
    d3 = make_float2(RH * (-d3.x - d3.y), RH * (d3.x - d3.y));  // *W8^-3
  }
  float2 t0 = cadd(s0, s2), t1 = csub(s0, s2), t2 = cadd(s1, s3), t3 = csub(s1, s3);
  t3 = INV ? make_float2(-t3.y, t3.x) : make_float2(t3.y, -t3.x);
  float2 E0 = cadd(t0, t2), E1 = cadd(t1, t3), E2 = csub(t0, t2), E3 = csub(t1, t3);
  t0 = cadd(d0, d2); t1 = csub(d0, d2); t2 = cadd(d1, d3); t3 = csub(d1, d3);
  t3 = INV ? make_float2(-t3.y, t3.x) : make_float2(t3.y, -t3.x);
  r[0] = E0; r[2] = E1; r[4] = E2; r[6] = E3;
  r[1] = cadd(t0, t2); r[3] = cadd(t1, t3); r[5] = csub(t0, t2); r[7] = csub(t1, t3);
}

// 512-pt FFT, one wave per line, data in 8 regs. tw[k] = e^{-2pi i k/512}.
// Forward: input r[a] = x[64a + j] -> lane 8c+e, reg f holds X[c + 8e + 64f]
// (bitswap-lanes => lane-linear). Inverse: conjugate graph, same geometry.
template <bool INV>
__device__ void fft512_reg(float2 r[8], float* ere, float* eim, const float2* tw, int j) {
  const int hi = j >> 3, lo = j & 7;
  dft8<INV>(r);                         // over a -> regs c
  #pragma unroll
  for (int c = 1; c < 8; ++c) {         // twiddle W64^{b c}
    float2 w = tw[(8 * hi * c) & 511];
    if (INV) w.y = -w.y;
    r[c] = cmul(r[c], w);
  }
  #pragma unroll
  for (int c = 0; c < 8; ++c) { int a = ex1(c, hi, lo); ere[a] = r[c].x; eim[a] = r[c].y; }
  wsync();
  #pragma unroll
  for (int b = 0; b < 8; ++b) { int a = ex1(hi, b, lo); r[b] = make_float2(ere[a], eim[a]); }
  dft8<INV>(r);                         // over b -> regs e
  {                                     // twiddle W512^{g(c+8e)} via recurrence
    float2 base = tw[(lo * hi) & 511];
    float2 step = tw[(8 * lo) & 511];
    if (INV) { base.y = -base.y; step.y = -step.y; }
    #pragma unroll
    for (int e = 0; e < 8; ++e) { r[e] = cmul(r[e], base); base = cmul(base, step); }
  }
  wsync();                              // ex1 reads must precede ex2 writes
  #pragma unroll
  for (int e = 0; e < 8; ++e) { int a = ex2(hi, e, lo); ere[a] = r[e].x; eim[a] = r[e].y; }
  wsync();
  #pragma unroll
  for (int g = 0; g < 8; ++g) { int a = ex2(hi, lo, g); r[g] = make_float2(ere[a], eim[a]); }
  dft8<INV>(r);                         // over g -> regs f
}

// lane bit-swap (hi3<->lo3): converts (c,e)-lane layout <-> lane-linear layout.
__device__ __forceinline__ void bitswap_lanes(float2 r[8], int j) {
  int src = ((j & 7) << 3) | (j >> 3);
  #pragma unroll
  for (int f = 0; f < 8; ++f) {
    r[f].x = __shfl(r[f].x, src);
    r[f].y = __shfl(r[f].y, src);
  }
}

__device__ __forceinline__ void fill_tw(float2* tw, int t) {
  float s, c;
  float ang = -TWO_PI * (float)t / (float)FFT_N;
  sincosf(ang, &s, &c); tw[t] = make_float2(c, s);
  ang = -TWO_PI * (float)(t + 256) / (float)FFT_N;
  sincosf(ang, &s, &c); tw[t + 256] = make_float2(c, s);
}

// PSF row-DFT, transposed: St[img][v][i] = sum_j f[i][j] e^{-2pi i v(j-7)/512},
// v in [0,256]. Contiguous 15-float2 run per (img,v).
__global__ __launch_bounds__(256) void k_psf(
    const float* __restrict__ filters, float2* __restrict__ St) {
  __shared__ float fs[KK];
  int img = blockIdx.x;
  int t = threadIdx.x;
  if (t < KK) fs[t] = filters[(size_t)img * KK + t];
  __syncthreads();
  for (int v = t; v < NV; v += 256) {
    float cs[KSZ], sn[KSZ];
    #pragma unroll
    for (int jj = 0; jj < KSZ; ++jj) {
      float ang = -TWO_PI * (float)(v * (jj - 7)) / (float)FFT_N;
      sincosf(ang, &sn[jj], &cs[jj]);
    }
    float2* dst = St + ((size_t)img * NV + v) * KSZ;
    #pragma unroll
    for (int i = 0; i < KSZ; ++i) {
      float2 s = make_float2(0.f, 0.f);
      #pragma unroll
      for (int jj = 0; jj < KSZ; ++jj) {
        float fv = fs[i * KSZ + jj];
        s.x += fv * cs[jj];
        s.y += fv * sn[jj];
      }
      dst[i] = s;
    }
  }
}

// Row FFT of packed pair (z = yA + i yB) + Hermitian unpack; writes per-image
// half-spectrum planes zh[img][row][v] (row stride RS). ONE ROW PER WAVE.
__global__ __launch_bounds__(256) void k_rows_fwd(
    const float* __restrict__ y, float2* __restrict__ zh, int pairBase) {
  __shared__ float ere[4][EXSZ], eim[4][EXSZ];
  __shared__ float2 tw[512];
  int t = threadIdx.x;
  int w = __builtin_amdgcn_readfirstlane(t >> 6);
  int j = t & 63;
  fill_tw(tw, t);
  __syncthreads();
  int line = blockIdx.x * 4 + w;              // chunk-local: pair p, row
  int p = line >> 9, row = line & 511;
  int gp = pairBase + p;
  const float* rA = y + (size_t)(2 * gp) * IMG_PIX + (size_t)row * FFT_N;
  const float* rB = rA + IMG_PIX;
  float2* plA = zh + (size_t)(2 * p) * PLANE;   // chunk-local planes
  float2* plB = plA + PLANE;
  float2 r[8];
  #pragma unroll
  for (int a = 0; a < 8; ++a) r[a] = make_float2(rA[64 * a + j], rB[64 * a + j]);
  fft512_reg<false>(r, ere[w], eim[w], tw, j);
  bitswap_lanes(r, j);                 // lane j reg f  <->  Z[64f + j]
  float2 m[8];
  int msrc = (64 - j) & 63;
  #pragma unroll
  for (int f = 0; f < 8; ++f) { m[f].x = __shfl(r[f].x, msrc); m[f].y = __shfl(r[f].y, msrc); }
  float2* wA = plA + (size_t)row * RS;
  float2* wB = plB + (size_t)row * RS;
  #pragma unroll
  for (int f = 0; f < 5; ++f) {
    int v = 64 * f + j;
    float2 Zp = r[f];
    float2 Zm = (j == 0) ? m[(8 - f) & 7] : m[7 - f];   // Z[(512 - v) & 511]
    float2 ya = make_float2(0.5f * (Zp.x + Zm.x), 0.5f * (Zp.y - Zm.y));
    float2 yb = make_float2(0.5f * (Zp.y + Zm.y), 0.5f * (Zm.x - Zp.x));
    if (v <= 256) { wA[v] = ya; wB[v] = yb; }
  }
}

// Fused column pass WITH embedded layout flips: 512 threads / 8 waves, 16
// columns per block (2 per wave). Gather via LDS 128B-segment staging,
// fwd FFT + Wiener + inv FFT in registers, scatter back. In place.
__global__ __launch_bounds__(512) void k_col_wiener(
    float2* __restrict__ zh, const float2* __restrict__ St, int imgBase) {
  __shared__ float ere[8][EXSZ], eim[8][EXSZ];
  __shared__ float2 tw[512];
  __shared__ float tre[64][17], tim[64][17];   // SoA tile: stride 17 => <=2-way banks
  int t = threadIdx.x;
  int w = __builtin_amdgcn_readfirstlane(t >> 6);   // 0..7
  int j = t & 63;
  {                                            // 512 threads: one tw entry each
    float s, c;
    sincosf(-TWO_PI * (float)t / (float)FFT_N, &s, &c);
    tw[t] = make_float2(c, s);
  }
  int img_l = blockIdx.x / 17, vg = blockIdx.x % 17;
  int img = imgBase + img_l;
  int vbase = vg * 16;
  int ncols = (vg == 16) ? 1 : 16;
  float2* pl = zh + (size_t)img_l * PLANE;
  const float SC = 1.f / (float)IMG_PIX;
  int vi = t & 15, ri0 = t >> 4;               // ri0 0..31
  float2 rq[2][8];                             // 2 columns x 8 regs, static idx only
  __syncthreads();                             // tw visible
  // ---- gather: 8 row-chunks of [64 rows x ncols]
  #pragma unroll
  for (int a = 0; a < 8; ++a) {
    #pragma unroll
    for (int rr = 0; rr < 2; ++rr) {
      int ri = ri0 + 32 * rr;
      if (vi < ncols) {
        float2 z = pl[(size_t)(64 * a + ri) * RS + vbase + vi];
        tre[ri][vi] = z.x; tim[ri][vi] = z.y;
      }
    }
    __syncthreads();
    #pragma unroll
    for (int q = 0; q < 2; ++q) {
      int c = w * 2 + q;
      int cc = (c < ncols) ? c : 0;
      rq[q][a] = make_float2(tre[j][cc], tim[j][cc]);
    }
    __syncthreads();
  }
  // ---- compute: per-column fwd FFT + Wiener + inv FFT (wave-local only)
  #pragma unroll
  for (int q = 0; q < 2; ++q) {
    int c = w * 2 + q;
    int v = vbase + c;                         // wave-uniform
    bool ok = (v <= 256) && (c < ncols);
    if (ok) {
      fft512_reg<false>(rq[q], ere[w], eim[w], tw, j);
      const float2* sp = St + ((size_t)img * NV + v) * KSZ;
      int u0 = (j >> 3) + 8 * (j & 7);         // fwd-output layout: u = u0+64f
      float2 G[8];
      #pragma unroll
      for (int m = 0; m < 8; ++m) G[m] = make_float2(0.f, 0.f);
      #pragma unroll
      for (int i = 0; i < KSZ; ++i) {
        float2 wb = tw[(u0 * (i - 7)) & 511];  // e^{-2pi i u0(i-7)/512}
        float2 b = cmul(sp[i], wb);
        int m = (i + 1) & 7;                   // (i-7) mod 8
        G[m] = cadd(G[m], b);
      }
      dft8<false>(G);                          // G[f] = H(u0 + 64f)
      float lv = 2.f - 2.f * tw[v].x;
      #pragma unroll
      for (int f = 0; f < 8; ++f) {
        int u = u0 + 64 * f;
        float2 H = G[f];
        float lap = (2.f - 2.f * tw[u].x) + lv;
        float inv = SC / (H.x * H.x + H.y * H.y + BAL * lap * lap);
        float2 Z = rq[q][f];
        rq[q][f] = make_float2((H.x * Z.x + H.y * Z.y) * inv,
                               (H.x * Z.y - H.y * Z.x) * inv);
      }
      bitswap_lanes(rq[q], j);                 // -> lane-linear u for inverse
      fft512_reg<true>(rq[q], ere[w], eim[w], tw, j);
      bitswap_lanes(rq[q], j);                 // -> lane-linear rows: reg f = row 64f+j
    }
  }
  // ---- scatter: 8 row-chunks back to the row-major plane
  #pragma unroll
  for (int f = 0; f < 8; ++f) {
    #pragma unroll
    for (int q = 0; q < 2; ++q) {
      int c = w * 2 + q;
      if (c < ncols && vbase + c <= 256) { tre[j][c] = rq[q][f].x; tim[j][c] = rq[q][f].y; }
    }
    __syncthreads();
    #pragma unroll
    for (int rr = 0; rr < 2; ++rr) {
      int ri = ri0 + 32 * rr;
      if (vi < ncols) {
        pl[(size_t)(64 * f + ri) * RS + vbase + vi] = make_float2(tre[ri][vi], tim[ri][vi]);
      }
    }
    __syncthreads();
  }
}

// Hermitian repack + inverse row FFT + clip/store both images (1/N^2 already
// folded into the Wiener multiply). ONE ROW PER WAVE.
__global__ __launch_bounds__(256) void k_rows_inv(
    const float2* __restrict__ zh, float* __restrict__ out, int pairBase) {
  __shared__ float ere[4][EXSZ], eim[4][EXSZ];
  __shared__ float2 tw[512];
  int t = threadIdx.x;
  int w = __builtin_amdgcn_readfirstlane(t >> 6);
  int j = t & 63;
  fill_tw(tw, t);
  __syncthreads();
  int line = blockIdx.x * 4 + w;
  int p = line >> 9, row = line & 511;
  int gp = pairBase + p;
  const float2* rA = zh + (size_t)(2 * p) * PLANE + (size_t)row * RS;
  const float2* rB = rA + PLANE;
  float* oA = out + (size_t)(2 * gp) * IMG_PIX + (size_t)row * FFT_N;
  float* oB = oA + IMG_PIX;
  float2 r[8];
  #pragma unroll
  for (int a = 0; a < 8; ++a) {
    int n = 64 * a + j;
    if (n <= 256) {
      float2 ya = rA[n], yb = rB[n];
      r[a] = make_float2(ya.x - yb.y, ya.y + yb.x);        // YA + i YB
    } else {
      int n2 = 512 - n;
      float2 ya = rA[n2], yb = rB[n2];
      r[a] = make_float2(ya.x + yb.y, yb.x - ya.y);        // conj(YA)+i conj(YB)
    }
  }
  fft512_reg<true>(r, ere[w], eim[w], tw, j);
  bitswap_lanes(r, j);                  // lane j reg f <-> pixel 64f + j
  #pragma unroll
  for (int f = 0; f < 8; ++f) {
    int px = 64 * f + j;
    oA[px] = fminf(1.f, fmaxf(-1.f, r[f].x));
    oB[px] = fminf(1.f, fmaxf(-1.f, r[f].y));
  }
}

extern "C" void kernel_launch(void* const* d_in, const int* in_sizes, int n_in,
                              void* d_out, int out_size, void* d_ws, size_t ws_size,
                              hipStream_t stream) {
  const float* y       = (const float*)d_in[0];
  const float* filters = (const float*)d_in[1];
  float* out = (float*)d_out;

  // ws: [St: 48*257*15 f2 = 1.48MB][zh: chunk pairs * 2 planes (row stride RS)]
  size_t sElems = (size_t)NIMG * NV * KSZ;
  float2* St = (float2*)d_ws;
  size_t sBytes = sElems * sizeof(float2);
  size_t zBytes = (ws_size > sBytes) ? (ws_size - sBytes) : 0;
  size_t perPair = 2 * PLANE * sizeof(float2);   // ~2.16 MiB
  int chunk = (int)(zBytes / perPair);
  if (chunk > NPAIR) chunk = NPAIR;
  if (chunk < 1)     chunk = 1;
  float2* zh = St + sElems;

  k_psf<<<NIMG, 256, 0, stream>>>(filters, St);

  for (int p0 = 0; p0 < NPAIR; p0 += chunk) {
    int nc = (chunk < NPAIR - p0) ? chunk : (NPAIR - p0);
    k_rows_fwd  <<<nc * 128,    256, 0, stream>>>(y, zh, p0);
    k_col_wiener<<<2 * nc * 17, 512, 0, stream>>>(zh, St, 2 * p0);
    k_rows_inv  <<<nc * 128,    256, 0, stream>>>(zh, out, p0);
  }
}

// Round 9
// 164.813 us; speedup vs baseline: 1.7875x; 1.0408x over previous
//
#include <hip/hip_runtime.h>
#include <cstddef>
#include <cmath>

#define FFT_N    512
#define IMG_PIX  (FFT_N * FFT_N)
#define NIMG     48          // B*C
#define NPAIR    24
#define KSZ      15
#define KK       (KSZ * KSZ)
#define BAL      0.1f
#define TWO_PI   6.283185307179586f
#define NV       257                         // rfft half-width (v = 0..256)
#define PLANE    ((size_t)NV * FFT_N)        // v-major plane: zh[img][v][row]
#define EXSZ     576                         // per-wave exchange buffer (floats)

__device__ __forceinline__ float2 cadd(float2 a, float2 b) { return make_float2(a.x + b.x, a.y + b.y); }
__device__ __forceinline__ float2 csub(float2 a, float2 b) { return make_float2(a.x - b.x, a.y - b.y); }
__device__ __forceinline__ float2 cmul(float2 a, float2 b) {
  return make_float2(a.x * b.x - a.y * b.y, a.x * b.y + a.y * b.x);
}
__device__ __forceinline__ int ex1(int c, int b, int g) { return 72 * c + 8 * b + g; }
__device__ __forceinline__ int ex2(int c, int e, int g) { return 72 * c + 9 * e + g; }

// Wave-local ordering fence (exchange buffers are wave-private).
__device__ __forceinline__ void wsync() {
  asm volatile("" ::: "memory");
  __builtin_amdgcn_wave_barrier();
  asm volatile("" ::: "memory");
}

// DFT8 over the 8 registers: out[k] = sum_a in[a] e^{-+2pi i a k/8} (INV => +).
template <bool INV>
__device__ __forceinline__ void dft8(float2 r[8]) {
  const float RH = 0.70710678118654752440f;
  float2 s0 = cadd(r[0], r[4]), s1 = cadd(r[1], r[5]), s2 = cadd(r[2], r[6]), s3 = cadd(r[3], r[7]);
  float2 d0 = csub(r[0], r[4]), d1 = csub(r[1], r[5]), d2 = csub(r[2], r[6]), d3 = csub(r[3], r[7]);
  if (!INV) {
    d1 = make_float2(RH * (d1.x + d1.y), RH * (d1.y - d1.x));   // *W8^1
    d2 = make_float2(d2.y, -d2.x);                              // *-i
    d3 = make_float2(RH * (d3.y - d3.x), RH * (-d3.x - d3.y));  // *W8^3
  } else {
    d1 = make_float2(RH * (d1.x - d1.y), RH * (d1.x + d1.y));   // *W8^-1
    d2 = make_float2(-d2.y, d2.x);                              // *+i
    d3 = make_float2(RH * (-d3.x - d3.y), RH * (d3.x - d3.y));  // *W8^-3
  }
  float2 t0 = cadd(s0, s2), t1 = csub(s0, s2), t2 = cadd(s1, s3), t3 = csub(s1, s3);
  t3 = INV ? make_float2(-t3.y, t3.x) : make_float2(t3.y, -t3.x);
  float2 E0 = cadd(t0, t2), E1 = cadd(t1, t3), E2 = csub(t0, t2), E3 = csub(t1, t3);
  t0 = cadd(d0, d2); t1 = csub(d0, d2); t2 = cadd(d1, d3); t3 = csub(d1, d3);
  t3 = INV ? make_float2(-t3.y, t3.x) : make_float2(t3.y, -t3.x);
  r[0] = E0; r[2] = E1; r[4] = E2; r[6] = E3;
  r[1] = cadd(t0, t2); r[3] = cadd(t1, t3); r[5] = csub(t0, t2); r[7] = csub(t1, t3);
}

// 512-pt FFT, one wave per line, data in 8 regs. tw[k] = e^{-2pi i k/512}.
// Forward: input r[a] = x[64a + j] -> lane 8c+e, reg f holds X[c + 8e + 64f]
// (bitswap-lanes => lane-linear). Inverse: conjugate graph, same geometry.
template <bool INV>
__device__ void fft512_reg(float2 r[8], float* ere, float* eim, const float2* tw, int j) {
  const int hi = j >> 3, lo = j & 7;
  dft8<INV>(r);                         // over a -> regs c
  #pragma unroll
  for (int c = 1; c < 8; ++c) {         // twiddle W64^{b c}
    float2 w = tw[(8 * hi * c) & 511];
    if (INV) w.y = -w.y;
    r[c] = cmul(r[c], w);
  }
  #pragma unroll
  for (int c = 0; c < 8; ++c) { int a = ex1(c, hi, lo); ere[a] = r[c].x; eim[a] = r[c].y; }
  wsync();
  #pragma unroll
  for (int b = 0; b < 8; ++b) { int a = ex1(hi, b, lo); r[b] = make_float2(ere[a], eim[a]); }
  dft8<INV>(r);                         // over b -> regs e
  {                                     // twiddle W512^{g(c+8e)} via recurrence
    float2 base = tw[(lo * hi) & 511];
    float2 step = tw[(8 * lo) & 511];
    if (INV) { base.y = -base.y; step.y = -step.y; }
    #pragma unroll
    for (int e = 0; e < 8; ++e) { r[e] = cmul(r[e], base); base = cmul(base, step); }
  }
  wsync();                              // ex1 reads must precede ex2 writes
  #pragma unroll
  for (int e = 0; e < 8; ++e) { int a = ex2(hi, e, lo); ere[a] = r[e].x; eim[a] = r[e].y; }
  wsync();
  #pragma unroll
  for (int g = 0; g < 8; ++g) { int a = ex2(hi, lo, g); r[g] = make_float2(ere[a], eim[a]); }
  dft8<INV>(r);                         // over g -> regs f
}

// lane bit-swap (hi3<->lo3): converts (c,e)-lane layout <-> lane-linear layout.
__device__ __forceinline__ void bitswap_lanes(float2 r[8], int j) {
  int src = ((j & 7) << 3) | (j >> 3);
  #pragma unroll
  for (int f = 0; f < 8; ++f) {
    r[f].x = __shfl(r[f].x, src);
    r[f].y = __shfl(r[f].y, src);
  }
}

__device__ __forceinline__ void fill_tw(float2* tw, int t) {
  float s, c;
  float ang = -TWO_PI * (float)t / (float)FFT_N;
  sincosf(ang, &s, &c); tw[t] = make_float2(c, s);
  ang = -TWO_PI * (float)(t + 256) / (float)FFT_N;
  sincosf(ang, &s, &c); tw[t + 256] = make_float2(c, s);
}

// PSF row-DFT, transposed: St[img][v][i] = sum_j f[i][j] e^{-2pi i v(j-7)/512},
// v in [0,256]. Contiguous 15-float2 run per (img,v).
__global__ __launch_bounds__(256) void k_psf(
    const float* __restrict__ filters, float2* __restrict__ St) {
  __shared__ float fs[KK];
  int img = blockIdx.x;
  int t = threadIdx.x;
  if (t < KK) fs[t] = filters[(size_t)img * KK + t];
  __syncthreads();
  for (int v = t; v < NV; v += 256) {
    float cs[KSZ], sn[KSZ];
    #pragma unroll
    for (int jj = 0; jj < KSZ; ++jj) {
      float ang = -TWO_PI * (float)(v * (jj - 7)) / (float)FFT_N;
      sincosf(ang, &sn[jj], &cs[jj]);
    }
    float2* dst = St + ((size_t)img * NV + v) * KSZ;
    #pragma unroll
    for (int i = 0; i < KSZ; ++i) {
      float2 s = make_float2(0.f, 0.f);
      #pragma unroll
      for (int jj = 0; jj < KSZ; ++jj) {
        float fv = fs[i * KSZ + jj];
        s.x += fv * cs[jj];
        s.y += fv * sn[jj];
      }
      dst[i] = s;
    }
  }
}

// Row FFT of packed pair (z = yA + i yB) + Hermitian unpack + TRANSPOSED
// (v-major) store via LDS tile. 512 threads = 8 waves = 8 rows per block.
__global__ __launch_bounds__(512) void k_rows_fwd(
    const float* __restrict__ y, float2* __restrict__ zh, int pairBase) {
  __shared__ float ere[8][EXSZ], eim[8][EXSZ];
  __shared__ float2 tw[512];
  __shared__ float2 tA[8][72], tB[8][72];      // [row][v-in-chunk], pad 72
  int t = threadIdx.x;
  int w = __builtin_amdgcn_readfirstlane(t >> 6);
  int j = t & 63;
  {
    float s, c;
    sincosf(-TWO_PI * (float)t / (float)FFT_N, &s, &c);
    tw[t] = make_float2(c, s);
  }
  __syncthreads();
  int p = blockIdx.x >> 6, rg = blockIdx.x & 63;
  int gp = pairBase + p;
  int row0 = rg * 8;
  int row = row0 + w;
  const float* rA = y + (size_t)(2 * gp) * IMG_PIX + (size_t)row * FFT_N;
  const float* rB = rA + IMG_PIX;
  float2* plA = zh + (size_t)(2 * p) * PLANE;   // chunk-local planes (v-major)
  float2* plB = plA + PLANE;
  float2 r[8];
  #pragma unroll
  for (int a = 0; a < 8; ++a) r[a] = make_float2(rA[64 * a + j], rB[64 * a + j]);
  fft512_reg<false>(r, ere[w], eim[w], tw, j);
  bitswap_lanes(r, j);                 // lane j reg f  <->  Z[64f + j]
  float2 m[8];
  int msrc = (64 - j) & 63;
  #pragma unroll
  for (int f = 0; f < 8; ++f) { m[f].x = __shfl(r[f].x, msrc); m[f].y = __shfl(r[f].y, msrc); }
  int vi = t >> 3, ri = t & 7;
  #pragma unroll
  for (int c = 0; c < 4; ++c) {        // v-chunks [64c, 64c+64)
    float2 Zp = r[c];
    float2 Zm = (j == 0) ? m[(8 - c) & 7] : m[7 - c];   // Z[(512 - v) & 511]
    tA[w][j] = make_float2(0.5f * (Zp.x + Zm.x), 0.5f * (Zp.y - Zm.y));
    tB[w][j] = make_float2(0.5f * (Zp.y + Zm.y), 0.5f * (Zm.x - Zp.x));
    __syncthreads();
    int v = 64 * c + vi;
    plA[(size_t)v * FFT_N + row0 + ri] = tA[ri][vi];
    plB[(size_t)v * FFT_N + row0 + ri] = tB[ri][vi];
    __syncthreads();
  }
  if (j == 0) {                        // tail v = 256 (self-mirror slot)
    float2 Zp = r[4], Zm = m[4];
    plA[(size_t)256 * FFT_N + row] = make_float2(0.5f * (Zp.x + Zm.x), 0.5f * (Zp.y - Zm.y));
    plB[(size_t)256 * FFT_N + row] = make_float2(0.5f * (Zp.y + Zm.y), 0.5f * (Zm.x - Zp.x));
  }
}

// Pure-streaming column pass: one wave per column (contiguous in v-major
// layout), fwd FFT + Wiener + inv FFT in registers, store back. No block
// barriers after the twiddle fill.
__global__ __launch_bounds__(256) void k_col_wiener(
    float2* __restrict__ zh, const float2* __restrict__ St, int imgBase) {
  __shared__ float ere[4][EXSZ], eim[4][EXSZ];
  __shared__ float2 tw[512];
  int t = threadIdx.x;
  int w = __builtin_amdgcn_readfirstlane(t >> 6);
  int j = t & 63;
  fill_tw(tw, t);
  __syncthreads();
  int img_l = blockIdx.x / 65, vg = blockIdx.x % 65;
  int v = vg * 4 + w;                          // wave-uniform
  if (v > 256) return;
  int img = imgBase + img_l;
  float2* col = zh + (size_t)img_l * PLANE + (size_t)v * FFT_N;
  const float SC = 1.f / (float)IMG_PIX;
  float2 r[8];
  #pragma unroll
  for (int a = 0; a < 8; ++a) r[a] = col[64 * a + j];
  fft512_reg<false>(r, ere[w], eim[w], tw, j);
  {
    const float2* sp = St + ((size_t)img * NV + v) * KSZ;   // uniform -> s_load
    int u0 = (j >> 3) + 8 * (j & 7);           // fwd-output layout: u = u0+64f
    float2 G[8];
    #pragma unroll
    for (int m = 0; m < 8; ++m) G[m] = make_float2(0.f, 0.f);
    #pragma unroll
    for (int i = 0; i < KSZ; ++i) {
      float2 wb = tw[(u0 * (i - 7)) & 511];    // e^{-2pi i u0(i-7)/512}
      float2 b = cmul(sp[i], wb);
      int m = (i + 1) & 7;                     // (i-7) mod 8
      G[m] = cadd(G[m], b);
    }
    dft8<false>(G);                            // G[f] = H(u0 + 64f)
    float lv = 2.f - 2.f * tw[v].x;
    #pragma unroll
    for (int f = 0; f < 8; ++f) {
      int u = u0 + 64 * f;
      float2 H = G[f];
      float lap = (2.f - 2.f * tw[u].x) + lv;
      float inv = SC / (H.x * H.x + H.y * H.y + BAL * lap * lap);
      float2 Z = r[f];
      r[f] = make_float2((H.x * Z.x + H.y * Z.y) * inv,
                         (H.x * Z.y - H.y * Z.x) * inv);
    }
  }
  bitswap_lanes(r, j);                  // -> lane-linear u for the inverse
  fft512_reg<true>(r, ere[w], eim[w], tw, j);
  bitswap_lanes(r, j);                  // -> lane-linear rows: reg f = row 64f+j
  #pragma unroll
  for (int f = 0; f < 8; ++f) col[64 * f + j] = r[f];
}

// Bulk LDS-staged v-major read + Hermitian repack + inverse row FFT +
// clip/store both images. 512 threads = 8 waves = 8 rows per block.
__global__ __launch_bounds__(512) void k_rows_inv(
    const float2* __restrict__ zh, float* __restrict__ out, int pairBase) {
  __shared__ float ere[8][EXSZ], eim[8][EXSZ];
  __shared__ float2 tw[512];
  __shared__ float2 tA[NV][9], tB[NV][9];      // [v][row-in-block], pad 9
  int t = threadIdx.x;
  int w = __builtin_amdgcn_readfirstlane(t >> 6);
  int j = t & 63;
  {
    float s, c;
    sincosf(-TWO_PI * (float)t / (float)FFT_N, &s, &c);
    tw[t] = make_float2(c, s);
  }
  int p = blockIdx.x >> 6, rg = blockIdx.x & 63;
  int gp = pairBase + p;
  int row0 = rg * 8;
  const float2* plA = zh + (size_t)(2 * p) * PLANE;
  const float2* plB = plA + PLANE;
  for (int idx = t; idx < NV * 8; idx += 512) {
    int v = idx >> 3, ri = idx & 7;
    tA[v][ri] = plA[(size_t)v * FFT_N + row0 + ri];
    tB[v][ri] = plB[(size_t)v * FFT_N + row0 + ri];
  }
  __syncthreads();
  float2 r[8];
  #pragma unroll
  for (int a = 0; a < 8; ++a) {
    int n = 64 * a + j;
    bool mir = (n > 256);
    int nn = mir ? (512 - n) : n;
    float2 ya = tA[nn][w], yb = tB[nn][w];
    r[a] = mir ? make_float2(ya.x + yb.y, yb.x - ya.y)   // conj(YA)+i conj(YB)
               : make_float2(ya.x - yb.y, ya.y + yb.x);  // YA + i YB
  }
  fft512_reg<true>(r, ere[w], eim[w], tw, j);
  bitswap_lanes(r, j);                  // lane j reg f <-> pixel 64f + j
  float* oA = out + (size_t)(2 * gp) * IMG_PIX + (size_t)(row0 + w) * FFT_N;
  float* oB = oA + IMG_PIX;
  #pragma unroll
  for (int f = 0; f < 8; ++f) {
    int px = 64 * f + j;
    oA[px] = fminf(1.f, fmaxf(-1.f, r[f].x));
    oB[px] = fminf(1.f, fmaxf(-1.f, r[f].y));
  }
}

extern "C" void kernel_launch(void* const* d_in, const int* in_sizes, int n_in,
                              void* d_out, int out_size, void* d_ws, size_t ws_size,
                              hipStream_t stream) {
  const float* y       = (const float*)d_in[0];
  const float* filters = (const float*)d_in[1];
  float* out = (float*)d_out;

  // ws: [St: 48*257*15 f2 = 1.48MB][zh: chunk pairs * 2 v-major planes]
  size_t sElems = (size_t)NIMG * NV * KSZ;
  float2* St = (float2*)d_ws;
  size_t sBytes = sElems * sizeof(float2);
  size_t zBytes = (ws_size > sBytes) ? (ws_size - sBytes) : 0;
  size_t perPair = 2 * PLANE * sizeof(float2);   // ~2.1 MiB
  int chunk = (int)(zBytes / perPair);
  if (chunk > NPAIR) chunk = NPAIR;
  if (chunk < 1)     chunk = 1;
  float2* zh = St + sElems;

  k_psf<<<NIMG, 256, 0, stream>>>(filters, St);

  for (int p0 = 0; p0 < NPAIR; p0 += chunk) {
    int nc = (chunk < NPAIR - p0) ? chunk : (NPAIR - p0);
    k_rows_fwd  <<<nc * 64,     512, 0, stream>>>(y, zh, p0);
    k_col_wiener<<<2 * nc * 65, 256, 0, stream>>>(zh, St, 2 * p0);
    k_rows_inv  <<<nc * 64,     512, 0, stream>>>(zh, out, p0);
  }
}